// Round 12
// baseline (266.000 us; speedup 1.0000x reference)
//
#include <hip/hip_runtime.h>
#include <math.h>

// PrimitiveTokenizer round 12: R11 structure with BLOCK = 8 rows (512 slots),
// LDS ~78 KB -> 2 blocks/CU. Independent blocks overlap their serial phases
// (mechanism R9's same-barrier extra waves could not provide).
//  prep: weights -> bf16 hi/lo MFMA B-fragment planes in ws (unchanged).
//  mono: 512 blocks x 512 thr. stage -> parallel per-kind count/compact ->
//        barrier-free MLP chunk loop (FF in A-frag regs, 6 MFMA x 16 nt,
//        gelu, LDS fp32 atomic pool[8k][8r][260]) -> fuse A/B/C (M-tile rows
//        8-15 duplicate 0-7 via lr16&7; only rows 0-7 written) -> out.

#define W2F_HI   0
#define W2F_LO   524288
#define W1F_HI   1048576
#define W1F_LO   1179648
#define FW1F_HI  1310720
#define FW1F_LO  1507328
#define FW2F_HI  1703936
#define FW2F_LO  1769472

#define PSTR 260
#define WIN  512
#define ROWS 8

typedef __attribute__((ext_vector_type(8))) short frag;
typedef __attribute__((ext_vector_type(4))) float f32x4;

__device__ __forceinline__ unsigned short f2bf_rn(float x) {
    unsigned int u = __float_as_uint(x);
    unsigned int r = (u + 0x7fffu + ((u >> 16) & 1u)) >> 16;
    return (unsigned short)r;
}
__device__ __forceinline__ float bf2f(unsigned short h) {
    return __uint_as_float(((unsigned int)h) << 16);
}
__device__ __forceinline__ void split_bf(float x, unsigned short& h, unsigned short& l) {
    unsigned short hh = f2bf_rn(x);
    h = hh;
    l = f2bf_rn(x - bf2f(hh));
}

// |abs err| <= ~1.5e-7 (A&S 7.1.26 erf)
__device__ __forceinline__ float gelu_fast(float x) {
    float u = fabsf(x) * 0.7071067811865476f;
    float t = __builtin_amdgcn_rcpf(fmaf(0.3275911f, u, 1.0f));
    float p = fmaf(fmaf(fmaf(fmaf(1.061405429f, t, -1.453152027f), t,
                             1.421413741f), t, -0.284496736f), t, 0.254829592f) * t;
    float e = __expf(-u * u);
    float er = fmaf(-p, e, 1.0f);
    er = copysignf(er, x);
    return 0.5f * x * (1.0f + er);
}

// ---------------- prep: weights -> bf16 hi/lo fragment planes ----------------
__global__ __launch_bounds__(512) void prep_kernel(
    const float* __restrict__ w1, const float* __restrict__ w2,
    const float* __restrict__ fw1, const float* __restrict__ fw2,
    short* __restrict__ ws)
{
    int tid = blockIdx.x * 512 + threadIdx.x;
    int fid = tid >> 6, ln = tid & 63;
    if (fid >= 1792) return;
    int lr = ln & 15, kq = ln >> 4;
    float v[8];
    int dhi, dlo, dsto;
    if (fid < 1024) {                       // w2: [8k][8kst][16nt]
        int k = fid >> 7, kst = (fid >> 4) & 7, nt = fid & 15;
        int col = nt * 16 + lr;
        #pragma unroll
        for (int b = 0; b < 8; ++b) {
            int kg = kst * 32 + kq * 8 + b;
            v[b] = w2[(k * 256 + kg) * 256 + col];
        }
        dsto = fid * 512 + ln * 8; dhi = W2F_HI; dlo = W2F_LO;
    } else if (fid < 1280) {                // w1: [8k][2kst][16nt], K pad 48->64
        int f = fid - 1024;
        int k = f >> 5, kst = (f >> 4) & 1, nt = f & 15;
        int col = nt * 16 + lr;
        #pragma unroll
        for (int b = 0; b < 8; ++b) {
            int kg = kst * 32 + kq * 8 + b;
            v[b] = (kg < 48) ? w1[(k * 48 + kg) * 256 + col] : 0.0f;
        }
        dsto = f * 512 + ln * 8; dhi = W1F_HI; dlo = W1F_LO;
    } else if (fid < 1664) {                // fw1: [24kst][16nt]
        int f = fid - 1280;
        int kst = f >> 4, nt = f & 15;
        int col = nt * 16 + lr;
        #pragma unroll
        for (int b = 0; b < 8; ++b) {
            int kg = kst * 32 + kq * 8 + b;
            v[b] = fw1[kg * 256 + col];
        }
        dsto = f * 512 + ln * 8; dhi = FW1F_HI; dlo = FW1F_LO;
    } else {                                // fw2: [8kst][16nt]
        int f = fid - 1664;
        int kst = f >> 4, nt = f & 15;
        int col = nt * 16 + lr;
        #pragma unroll
        for (int b = 0; b < 8; ++b) {
            int kg = kst * 32 + kq * 8 + b;
            v[b] = fw2[kg * 256 + col];
        }
        dsto = f * 512 + ln * 8; dhi = FW2F_HI; dlo = FW2F_LO;
    }
    union { unsigned short u[8]; frag f; } hu, lu;
    #pragma unroll
    for (int b = 0; b < 8; ++b) split_bf(v[b], hu.u[b], lu.u[b]);
    *(frag*)(ws + dhi + dsto) = hu.f;
    *(frag*)(ws + dlo + dsto) = lu.f;
}

// ---------------- mono: MLP + pool + fuse, one block per 8 rows ----------------
__global__ __launch_bounds__(512, 4) void mono_kernel(
    const float* __restrict__ values, const int* __restrict__ kinds,
    const int* __restrict__ mask, const float* __restrict__ B_ff,
    const float* __restrict__ b1, const short* __restrict__ wsf,
    const int* __restrict__ pt, const int* __restrict__ lid,
    const float* __restrict__ meta, const float* __restrict__ type_emb,
    const float* __restrict__ layer_emb, const float* __restrict__ b2,
    const float* __restrict__ kind_emb, const float* __restrict__ fb1,
    const float* __restrict__ fb2, const float* __restrict__ meta_w,
    const float* __restrict__ meta_b, float* __restrict__ out)
{
    __shared__ __align__(16) float pool_ls[8 * ROWS * PSTR]; // 66.6 KB; head aliased by hz
    __shared__ float vals_ls[WIN];
    __shared__ unsigned char knd_ls[WIN], msk_ls[WIN];
    __shared__ unsigned short list[640];
    __shared__ short chunk_kind[48], chunk_base[48];
    __shared__ int totk_ls[8];
    __shared__ float b1_ls[2048];
    __shared__ float Bs_ls[24];
    __shared__ float cnt_ls[ROWS * 8], den_ls[ROWS], meta_ls[ROWS * 4];
    __shared__ int pt_ls[ROWS], lid_ls[ROWS];

    const int t = threadIdx.x, blk = blockIdx.x;
    const int wv = t >> 6, ln = t & 63, lr16 = ln & 15, kq = ln >> 4;
    const int gbase = blk * WIN, rb = blk * ROWS;

    const short* w1f_hi  = wsf + W1F_HI;
    const short* w1f_lo  = wsf + W1F_LO;
    const short* w2f_hi  = wsf + W2F_HI;
    const short* w2f_lo  = wsf + W2F_LO;
    const short* fw1f_hi = wsf + FW1F_HI;
    const short* fw1f_lo = wsf + FW1F_LO;
    const short* fw2f_hi = wsf + FW2F_HI;
    const short* fw2f_lo = wsf + FW2F_LO;

    // ---- prologue: stage ----
    {
        vals_ls[t] = values[gbase + t];
        knd_ls[t]  = (unsigned char)kinds[gbase + t];
        msk_ls[t]  = (unsigned char)mask[gbase + t];
    }
    #pragma unroll
    for (int i = 0; i < 4; ++i) b1_ls[t + i * 512] = b1[t + i * 512];
    if (t < 24) Bs_ls[t] = B_ff[t];
    if (t >= 32 && t < 32 + ROWS) { pt_ls[t - 32] = pt[rb + t - 32]; lid_ls[t - 32] = lid[rb + t - 32]; }
    if (t >= 64 && t < 64 + ROWS * 4) meta_ls[t - 64] = meta[rb * 4 + (t - 64)];
    for (int i = t; i < 8 * ROWS * PSTR; i += 512) pool_ls[i] = 0.0f;
    __syncthreads();

    // ---- pass 1 (parallel over 8 waves): wave k counts kind k per row ----
    {
        const int k = wv;
        int tot = 0;
        #pragma unroll 1
        for (int c = 0; c < ROWS; ++c) {
            int p = c * 64 + ln;
            int kd = knd_ls[p], mk = msk_ls[p];
            unsigned long long bal = __ballot(mk && (kd == k));
            int pc = __popcll(bal);
            if (ln == 0) cnt_ls[c * 8 + k] = (float)pc;
            tot += pc;
            if (k == 0) {
                unsigned long long balm = __ballot(mk != 0);
                if (ln == 0) {
                    int tm = __popcll(balm);
                    den_ls[c] = 1.0f / (float)(tm > 0 ? tm : 1);
                }
            }
        }
        if (ln == 0) totk_ls[k] = tot;
    }
    __syncthreads();

    // ---- per-thread offsets from totals ----
    int offe = 0, cbase = 0, nch = 0;
    #pragma unroll
    for (int j = 0; j < 8; ++j) {
        int pj = (totk_ls[j] + 15) & ~15;
        if (j < wv) { offe += pj; cbase += pj >> 4; }
        nch += pj >> 4;
    }

    // ---- pass 2 (parallel): wave k fills its list segment + pad + descs ----
    {
        const int k = wv;
        const unsigned long long below = (1ull << ln) - 1ull;
        int fill = 0;
        #pragma unroll 1
        for (int c = 0; c < ROWS; ++c) {
            int p = c * 64 + ln;
            int kd = knd_ls[p], mk = msk_ls[p];
            unsigned long long bal = __ballot(mk && (kd == k));
            if (mk && (kd == k)) list[offe + fill + __popcll(bal & below)] = (unsigned short)p;
            fill += __popcll(bal);
        }
        int padded = (fill + 15) & ~15;
        for (int i = fill + ln; i < padded; i += 64) list[offe + i] = 0xFFFFu;
        int nk = padded >> 4;
        for (int j = ln; j < nk; j += 64) {
            chunk_kind[cbase + j] = (short)k;
            chunk_base[cbase + j] = (short)(offe + j * 16);
        }
    }
    __syncthreads();

    // ---- barrier-free MLP loop: waves stride chunks ----
    for (int m = wv; m < nch; m += 8) {
        const int k = (int)chunk_kind[m];
        const int cb = (int)chunk_base[m];
        int slot = list[cb + lr16];
        float v = vals_ls[slot & (WIN - 1)];
        v = (slot == 0xFFFF) ? 0.0f : v;

        // FF directly into A-frag regs: lane(lr16,kq) = A[slot=lr16][kst*32+kq*8+b]
        frag ah[2], al[2];
        #pragma unroll
        for (int kst = 0; kst < 2; ++kst) {
            union { unsigned short u[8]; frag f; } hu, lu;
            int jb0 = kst * 32 + kq * 8;
            #pragma unroll
            for (int b = 0; b < 8; ++b) {
                int jb = jb0 + b;
                float sv;
                if (jb < 48) {
                    int jm = (jb < 24) ? jb : jb - 24;
                    float cadd = (jb < 24) ? 0.0f : 0.25f;   // cos = sin(x + 1/4 rev)
                    float rev = __builtin_amdgcn_fractf(fmaf(v, Bs_ls[jm], cadd));
                    sv = __builtin_amdgcn_sinf(rev);
                } else {
                    sv = 0.0f;                               // K-pad 48..63
                }
                split_bf(sv, hu.u[b], lu.u[b]);
            }
            ah[kst] = hu.f; al[kst] = lu.f;
        }

        int e4[4];
        #pragma unroll
        for (int r = 0; r < 4; ++r) {
            int sl = list[cb + kq * 4 + r];
            e4[r] = (sl == 0xFFFF) ? -1 : ((sl >> 6) & 7);
        }

        #pragma unroll 4
        for (int nt = 0; nt < 16; ++nt) {
            int o0 = ((k * 2 + 0) * 16 + nt) * 512 + ln * 8;
            int o1 = ((k * 2 + 1) * 16 + nt) * 512 + ln * 8;
            frag bh0 = *(const frag*)(w1f_hi + o0);
            frag bl0 = *(const frag*)(w1f_lo + o0);
            frag bh1 = *(const frag*)(w1f_hi + o1);
            frag bl1 = *(const frag*)(w1f_lo + o1);
            f32x4 acc = (f32x4)0.0f;
            acc = __builtin_amdgcn_mfma_f32_16x16x32_bf16(ah[0], bh0, acc, 0, 0, 0);
            acc = __builtin_amdgcn_mfma_f32_16x16x32_bf16(al[0], bh0, acc, 0, 0, 0);
            acc = __builtin_amdgcn_mfma_f32_16x16x32_bf16(ah[0], bl0, acc, 0, 0, 0);
            acc = __builtin_amdgcn_mfma_f32_16x16x32_bf16(ah[1], bh1, acc, 0, 0, 0);
            acc = __builtin_amdgcn_mfma_f32_16x16x32_bf16(al[1], bh1, acc, 0, 0, 0);
            acc = __builtin_amdgcn_mfma_f32_16x16x32_bf16(ah[1], bl1, acc, 0, 0, 0);
            float b1v = b1_ls[k * 256 + nt * 16 + lr16];
            #pragma unroll
            for (int r = 0; r < 4; ++r) {
                if (e4[r] >= 0) {
                    float g = gelu_fast(acc[r] + b1v);
                    atomicAdd(&pool_ls[(k * ROWS + e4[r]) * PSTR + nt * 16 + lr16], g);
                }
            }
        }
    }
    __syncthreads();

    // ---- fuse phase A: acc = sum_k pool[k] @ w2[k] (rows 8-15 duplicate 0-7) ----
    f32x4 acc[2];
    acc[0] = (f32x4)0.0f; acc[1] = (f32x4)0.0f;

    for (int k = 0; k < 8; ++k) {
        #pragma unroll 2
        for (int kst = 0; kst < 8; ++kst) {
            const float* pp = &pool_ls[(k * ROWS + (lr16 & 7)) * PSTR + kst * 32 + kq * 8];
            f32x4 u0 = *(const f32x4*)pp;
            f32x4 u1 = *(const f32x4*)(pp + 4);
            union { unsigned short u[8]; frag f; } hu, lu;
            #pragma unroll
            for (int b = 0; b < 4; ++b) {
                split_bf(u0[b], hu.u[b], lu.u[b]);
                split_bf(u1[b], hu.u[b + 4], lu.u[b + 4]);
            }
            frag ah = hu.f, al = lu.f;
            #pragma unroll
            for (int n = 0; n < 2; ++n) {
                int bo = ((k * 8 + kst) * 16 + (wv * 2 + n)) * 512 + ln * 8;
                frag bh = *(const frag*)(w2f_hi + bo);
                frag bl = *(const frag*)(w2f_lo + bo);
                acc[n] = __builtin_amdgcn_mfma_f32_16x16x32_bf16(ah, bh, acc[n], 0, 0, 0);
                acc[n] = __builtin_amdgcn_mfma_f32_16x16x32_bf16(al, bh, acc[n], 0, 0, 0);
                acc[n] = __builtin_amdgcn_mfma_f32_16x16x32_bf16(ah, bl, acc[n], 0, 0, 0);
            }
        }
    }
    __syncthreads();     // all pool reads done; hz aliases pool head

    float* hz = pool_ls; // [8][256] granule-XOR swizzled

    // ---- epilogue A: + cnt*(b2+kind_emb), * den -> hz (rows 0-7 only) ----
    if (kq < 2) {
        #pragma unroll
        for (int n = 0; n < 2; ++n) {
            int col = (wv * 2 + n) * 16 + lr16;
            float bks[8];
            #pragma unroll
            for (int k = 0; k < 8; ++k) bks[k] = b2[k * 256 + col] + kind_emb[k * 256 + col];
            #pragma unroll
            for (int r = 0; r < 4; ++r) {
                int row = kq * 4 + r;
                float hv = acc[n][r];
                #pragma unroll
                for (int k = 0; k < 8; ++k) hv = fmaf(cnt_ls[row * 8 + k], bks[k], hv);
                hv *= den_ls[row];
                hz[row * 256 + ((((col >> 2) ^ (row & 7)) << 2) | (col & 3))] = hv;
            }
        }
    }
    __syncthreads();

    // ---- phase B: z_pre = [h | type_emb | layer_emb] @ fw1 (K=768) ----
    f32x4 az[2];
    az[0] = (f32x4)0.0f; az[1] = (f32x4)0.0f;

    for (int kst = 0; kst < 24; ++kst) {
        const int row = lr16 & 7;
        union { unsigned short u[8]; frag f; } hu, lu;
        if (kst < 8) {
            int c0 = kst * 8 + kq * 2;
            f32x4 u0 = *(const f32x4*)&hz[row * 256 + ((c0 ^ row) << 2)];
            f32x4 u1 = *(const f32x4*)&hz[row * 256 + (((c0 + 1) ^ row) << 2)];
            #pragma unroll
            for (int b = 0; b < 4; ++b) {
                split_bf(u0[b], hu.u[b], lu.u[b]);
                split_bf(u1[b], hu.u[b + 4], lu.u[b + 4]);
            }
        } else {
            const float* eb = (kst < 16) ? type_emb : layer_emb;
            const int* ids = (kst < 16) ? pt_ls : lid_ls;
            int ko = (kst & 7) * 32 + kq * 8;
            const float* sp = eb + (size_t)ids[row] * 256 + ko;
            f32x4 u0 = *(const f32x4*)sp;
            f32x4 u1 = *(const f32x4*)(sp + 4);
            #pragma unroll
            for (int b = 0; b < 4; ++b) {
                split_bf(u0[b], hu.u[b], lu.u[b]);
                split_bf(u1[b], hu.u[b + 4], lu.u[b + 4]);
            }
        }
        frag ah = hu.f, al = lu.f;
        #pragma unroll
        for (int n = 0; n < 2; ++n) {
            int bo = (kst * 16 + (wv * 2 + n)) * 512 + ln * 8;
            frag bh = *(const frag*)(fw1f_hi + bo);
            frag bl = *(const frag*)(fw1f_lo + bo);
            az[n] = __builtin_amdgcn_mfma_f32_16x16x32_bf16(ah, bh, az[n], 0, 0, 0);
            az[n] = __builtin_amdgcn_mfma_f32_16x16x32_bf16(al, bh, az[n], 0, 0, 0);
            az[n] = __builtin_amdgcn_mfma_f32_16x16x32_bf16(ah, bl, az[n], 0, 0, 0);
        }
    }
    __syncthreads();     // all hz reads done

    if (kq < 2) {
        #pragma unroll
        for (int n = 0; n < 2; ++n) {
            int col = (wv * 2 + n) * 16 + lr16;
            float fb1v = fb1[col];
            #pragma unroll
            for (int r = 0; r < 4; ++r) {
                int row = kq * 4 + r;
                float z = gelu_fast(az[n][r] + fb1v);
                hz[row * 256 + ((((col >> 2) ^ row) << 2) | (col & 3))] = z;
            }
        }
    }
    __syncthreads();

    // ---- phase C: out = z @ fw2 + fb2 + meta @ meta_w + meta_b ----
    f32x4 ao2[2];
    ao2[0] = (f32x4)0.0f; ao2[1] = (f32x4)0.0f;

    for (int kst = 0; kst < 8; ++kst) {
        const int row = lr16 & 7;
        int c0 = kst * 8 + kq * 2;
        f32x4 u0 = *(const f32x4*)&hz[row * 256 + ((c0 ^ row) << 2)];
        f32x4 u1 = *(const f32x4*)&hz[row * 256 + (((c0 + 1) ^ row) << 2)];
        union { unsigned short u[8]; frag f; } hu, lu;
        #pragma unroll
        for (int b = 0; b < 4; ++b) {
            split_bf(u0[b], hu.u[b], lu.u[b]);
            split_bf(u1[b], hu.u[b + 4], lu.u[b + 4]);
        }
        frag ah = hu.f, al = lu.f;
        #pragma unroll
        for (int n = 0; n < 2; ++n) {
            int bo = (kst * 16 + (wv * 2 + n)) * 512 + ln * 8;
            frag bh = *(const frag*)(fw2f_hi + bo);
            frag bl = *(const frag*)(fw2f_lo + bo);
            ao2[n] = __builtin_amdgcn_mfma_f32_16x16x32_bf16(ah, bh, ao2[n], 0, 0, 0);
            ao2[n] = __builtin_amdgcn_mfma_f32_16x16x32_bf16(al, bh, ao2[n], 0, 0, 0);
            ao2[n] = __builtin_amdgcn_mfma_f32_16x16x32_bf16(ah, bl, ao2[n], 0, 0, 0);
        }
    }

    if (kq < 2) {
        #pragma unroll
        for (int n = 0; n < 2; ++n) {
            int col = (wv * 2 + n) * 16 + lr16;
            float ob = fb2[col] + meta_b[col];
            float mw0 = meta_w[col], mw1 = meta_w[256 + col];
            float mw2 = meta_w[512 + col], mw3 = meta_w[768 + col];
            #pragma unroll
            for (int r = 0; r < 4; ++r) {
                int row = kq * 4 + r;
                float o = ao2[n][r] + ob;
                o = fmaf(meta_ls[row * 4 + 0], mw0, o);
                o = fmaf(meta_ls[row * 4 + 1], mw1, o);
                o = fmaf(meta_ls[row * 4 + 2], mw2, o);
                o = fmaf(meta_ls[row * 4 + 3], mw3, o);
                out[(size_t)(rb + row) * 256 + col] = o;
            }
        }
    }
}

extern "C" void kernel_launch(void* const* d_in, const int* in_sizes, int n_in,
                              void* d_out, int out_size, void* d_ws, size_t ws_size,
                              hipStream_t stream) {
    const float* values    = (const float*)d_in[0];
    const int*   kinds     = (const int*)d_in[1];
    const int*   mask      = (const int*)d_in[2];
    const int*   prim_type = (const int*)d_in[3];
    const int*   layer_id  = (const int*)d_in[4];
    const float* meta      = (const float*)d_in[5];
    const float* B_ff      = (const float*)d_in[6];
    const float* kind_emb  = (const float*)d_in[7];
    const float* type_emb  = (const float*)d_in[8];
    const float* layer_emb = (const float*)d_in[9];
    const float* mlp_w1    = (const float*)d_in[10];
    const float* mlp_b1    = (const float*)d_in[11];
    const float* mlp_w2    = (const float*)d_in[12];
    const float* mlp_b2    = (const float*)d_in[13];
    const float* fuse_w1   = (const float*)d_in[14];
    const float* fuse_b1   = (const float*)d_in[15];
    const float* fuse_w2   = (const float*)d_in[16];
    const float* fuse_b2   = (const float*)d_in[17];
    const float* meta_w    = (const float*)d_in[18];
    const float* meta_b    = (const float*)d_in[19];

    short* ws  = (short*)d_ws;
    float* out = (float*)d_out;

    prep_kernel<<<224, 512, 0, stream>>>(mlp_w1, mlp_w2, fuse_w1, fuse_w2, ws);
    mono_kernel<<<512, 512, 0, stream>>>(values, kinds, mask, B_ff, mlp_b1, ws,
                                         prim_type, layer_id, meta, type_emb,
                                         layer_emb, mlp_b2, kind_emb, fuse_b1,
                                         fuse_b2, meta_w, meta_b, out);
}

// Round 13
// 248.410 us; speedup vs baseline: 1.0708x; 1.0708x over previous
//
#include <hip/hip_runtime.h>
#include <math.h>

// PrimitiveTokenizer FINAL (revert to round-11 best: 248.99 us scored).
//  prep: 4 weight matrices -> bf16 hi/lo MFMA B-fragment planes in ws.
//  mono: 256 blocks x 512 thr, block = 16 rows = 1024 slots.
//        stage -> parallel per-kind count/compaction (wave k owns kind k) ->
//        barrier-free MLP chunk loop (FF computed directly into A-fragment
//        registers, 6 MFMA x 16 nt, gelu, LDS fp32 atomic pool[8][16][260]) ->
//        fuse phase A (sum_k pool@w2[k]) -> +cnt*(b2+kind_emb), /den -> hz ->
//        phase B ([h|type_emb|layer_emb]@fw1, gelu) -> phase C (@fw2 + meta
//        linear) -> out. No intermediate global traffic.
// Evidence trail: R9 (2x waves: flat), R10 (K-split less work: -60%), R12
// (2 blocks/CU: -7%) => ~250 us is a launch+DVFS+latency floor, not HBM/MFMA.

#define W2F_HI   0
#define W2F_LO   524288
#define W1F_HI   1048576
#define W1F_LO   1179648
#define FW1F_HI  1310720
#define FW1F_LO  1507328
#define FW2F_HI  1703936
#define FW2F_LO  1769472

#define PSTR 260    // pool row stride (floats)

typedef __attribute__((ext_vector_type(8))) short frag;
typedef __attribute__((ext_vector_type(4))) float f32x4;

__device__ __forceinline__ unsigned short f2bf_rn(float x) {
    unsigned int u = __float_as_uint(x);
    unsigned int r = (u + 0x7fffu + ((u >> 16) & 1u)) >> 16;
    return (unsigned short)r;
}
__device__ __forceinline__ float bf2f(unsigned short h) {
    return __uint_as_float(((unsigned int)h) << 16);
}
__device__ __forceinline__ void split_bf(float x, unsigned short& h, unsigned short& l) {
    unsigned short hh = f2bf_rn(x);
    h = hh;
    l = f2bf_rn(x - bf2f(hh));
}

// |abs err| <= ~1.5e-7 (A&S 7.1.26 erf)
__device__ __forceinline__ float gelu_fast(float x) {
    float u = fabsf(x) * 0.7071067811865476f;
    float t = __builtin_amdgcn_rcpf(fmaf(0.3275911f, u, 1.0f));
    float p = fmaf(fmaf(fmaf(fmaf(1.061405429f, t, -1.453152027f), t,
                             1.421413741f), t, -0.284496736f), t, 0.254829592f) * t;
    float e = __expf(-u * u);
    float er = fmaf(-p, e, 1.0f);
    er = copysignf(er, x);
    return 0.5f * x * (1.0f + er);
}

// ---------------- prep: weights -> bf16 hi/lo fragment planes ----------------
__global__ __launch_bounds__(512) void prep_kernel(
    const float* __restrict__ w1, const float* __restrict__ w2,
    const float* __restrict__ fw1, const float* __restrict__ fw2,
    short* __restrict__ ws)
{
    int tid = blockIdx.x * 512 + threadIdx.x;
    int fid = tid >> 6, ln = tid & 63;
    if (fid >= 1792) return;
    int lr = ln & 15, kq = ln >> 4;
    float v[8];
    int dhi, dlo, dsto;
    if (fid < 1024) {                       // w2: [8k][8kst][16nt]
        int k = fid >> 7, kst = (fid >> 4) & 7, nt = fid & 15;
        int col = nt * 16 + lr;
        #pragma unroll
        for (int b = 0; b < 8; ++b) {
            int kg = kst * 32 + kq * 8 + b;
            v[b] = w2[(k * 256 + kg) * 256 + col];
        }
        dsto = fid * 512 + ln * 8; dhi = W2F_HI; dlo = W2F_LO;
    } else if (fid < 1280) {                // w1: [8k][2kst][16nt], K pad 48->64
        int f = fid - 1024;
        int k = f >> 5, kst = (f >> 4) & 1, nt = f & 15;
        int col = nt * 16 + lr;
        #pragma unroll
        for (int b = 0; b < 8; ++b) {
            int kg = kst * 32 + kq * 8 + b;
            v[b] = (kg < 48) ? w1[(k * 48 + kg) * 256 + col] : 0.0f;
        }
        dsto = f * 512 + ln * 8; dhi = W1F_HI; dlo = W1F_LO;
    } else if (fid < 1664) {                // fw1: [24kst][16nt]
        int f = fid - 1280;
        int kst = f >> 4, nt = f & 15;
        int col = nt * 16 + lr;
        #pragma unroll
        for (int b = 0; b < 8; ++b) {
            int kg = kst * 32 + kq * 8 + b;
            v[b] = fw1[kg * 256 + col];
        }
        dsto = f * 512 + ln * 8; dhi = FW1F_HI; dlo = FW1F_LO;
    } else {                                // fw2: [8kst][16nt]
        int f = fid - 1664;
        int kst = f >> 4, nt = f & 15;
        int col = nt * 16 + lr;
        #pragma unroll
        for (int b = 0; b < 8; ++b) {
            int kg = kst * 32 + kq * 8 + b;
            v[b] = fw2[kg * 256 + col];
        }
        dsto = f * 512 + ln * 8; dhi = FW2F_HI; dlo = FW2F_LO;
    }
    union { unsigned short u[8]; frag f; } hu, lu;
    #pragma unroll
    for (int b = 0; b < 8; ++b) split_bf(v[b], hu.u[b], lu.u[b]);
    *(frag*)(ws + dhi + dsto) = hu.f;
    *(frag*)(ws + dlo + dsto) = lu.f;
}

// ---------------- mono: MLP + pool + fuse, one block per 16 rows ----------------
__global__ __launch_bounds__(512, 1) void mono_kernel(
    const float* __restrict__ values, const int* __restrict__ kinds,
    const int* __restrict__ mask, const float* __restrict__ B_ff,
    const float* __restrict__ b1, const short* __restrict__ wsf,
    const int* __restrict__ pt, const int* __restrict__ lid,
    const float* __restrict__ meta, const float* __restrict__ type_emb,
    const float* __restrict__ layer_emb, const float* __restrict__ b2,
    const float* __restrict__ kind_emb, const float* __restrict__ fb1,
    const float* __restrict__ fb2, const float* __restrict__ meta_w,
    const float* __restrict__ meta_b, float* __restrict__ out)
{
    __shared__ __align__(16) float pool_ls[8 * 16 * PSTR];  // 133 KB; head aliased by hz
    __shared__ float vals_ls[1024];
    __shared__ unsigned char knd_ls[1024], msk_ls[1024];
    __shared__ unsigned short list[1152];
    __shared__ short chunk_kind[80], chunk_base[80];
    __shared__ int totk_ls[8];
    __shared__ float b1_ls[2048];
    __shared__ float Bs_ls[24];
    __shared__ float cnt_ls[128], den_ls[16], meta_ls[64];
    __shared__ int pt_ls[16], lid_ls[16];

    const int t = threadIdx.x, blk = blockIdx.x;
    const int wv = t >> 6, ln = t & 63, lr16 = ln & 15, kq = ln >> 4;
    const int gbase = blk * 1024, rb = blk * 16;

    const short* w1f_hi  = wsf + W1F_HI;
    const short* w1f_lo  = wsf + W1F_LO;
    const short* w2f_hi  = wsf + W2F_HI;
    const short* w2f_lo  = wsf + W2F_LO;
    const short* fw1f_hi = wsf + FW1F_HI;
    const short* fw1f_lo = wsf + FW1F_LO;
    const short* fw2f_hi = wsf + FW2F_HI;
    const short* fw2f_lo = wsf + FW2F_LO;

    // ---- prologue: stage ----
    #pragma unroll
    for (int i = 0; i < 2; ++i) {
        int p = t + i * 512;
        vals_ls[p] = values[gbase + p];
        knd_ls[p]  = (unsigned char)kinds[gbase + p];
        msk_ls[p]  = (unsigned char)mask[gbase + p];
    }
    #pragma unroll
    for (int i = 0; i < 4; ++i) b1_ls[t + i * 512] = b1[t + i * 512];
    if (t < 24) Bs_ls[t] = B_ff[t];
    if (t >= 32 && t < 48) { pt_ls[t - 32] = pt[rb + t - 32]; lid_ls[t - 32] = lid[rb + t - 32]; }
    if (t >= 64 && t < 128) meta_ls[t - 64] = meta[rb * 4 + (t - 64)];
    for (int i = t; i < 8 * 16 * PSTR; i += 512) pool_ls[i] = 0.0f;
    __syncthreads();

    // ---- pass 1 (parallel over 8 waves): wave k counts kind k per row ----
    {
        const int k = wv;                        // chunk c == row c
        int tot = 0;
        #pragma unroll 1
        for (int c = 0; c < 16; ++c) {
            int p = c * 64 + ln;
            int kd = knd_ls[p], mk = msk_ls[p];
            unsigned long long bal = __ballot(mk && (kd == k));
            int pc = __popcll(bal);
            if (ln == 0) cnt_ls[c * 8 + k] = (float)pc;
            tot += pc;
            if (k == 0) {
                unsigned long long balm = __ballot(mk != 0);
                if (ln == 0) {
                    int tm = __popcll(balm);
                    den_ls[c] = 1.0f / (float)(tm > 0 ? tm : 1);
                }
            }
        }
        if (ln == 0) totk_ls[k] = tot;
    }
    __syncthreads();

    // ---- per-thread offsets from totals ----
    int offe = 0, cbase = 0, nch = 0;
    #pragma unroll
    for (int j = 0; j < 8; ++j) {
        int pj = (totk_ls[j] + 15) & ~15;
        if (j < wv) { offe += pj; cbase += pj >> 4; }
        nch += pj >> 4;
    }

    // ---- pass 2 (parallel): wave k fills its list segment + pad + descs ----
    {
        const int k = wv;
        const unsigned long long below = (1ull << ln) - 1ull;
        int fill = 0;
        #pragma unroll 1
        for (int c = 0; c < 16; ++c) {
            int p = c * 64 + ln;
            int kd = knd_ls[p], mk = msk_ls[p];
            unsigned long long bal = __ballot(mk && (kd == k));
            if (mk && (kd == k)) list[offe + fill + __popcll(bal & below)] = (unsigned short)p;
            fill += __popcll(bal);
        }
        int padded = (fill + 15) & ~15;
        for (int i = fill + ln; i < padded; i += 64) list[offe + i] = 0xFFFFu;
        int nk = padded >> 4;
        for (int j = ln; j < nk; j += 64) {
            chunk_kind[cbase + j] = (short)k;
            chunk_base[cbase + j] = (short)(offe + j * 16);
        }
    }
    __syncthreads();

    // ---- barrier-free MLP loop: waves stride chunks ----
    for (int m = wv; m < nch; m += 8) {
        const int k = (int)chunk_kind[m];
        const int cb = (int)chunk_base[m];
        int slot = list[cb + lr16];
        float v = vals_ls[slot & 1023];
        v = (slot == 0xFFFF) ? 0.0f : v;

        // FF directly into A-frag registers: lane(lr16,kq) = A[slot=lr16][kst*32+kq*8+b]
        frag ah[2], al[2];
        #pragma unroll
        for (int kst = 0; kst < 2; ++kst) {
            union { unsigned short u[8]; frag f; } hu, lu;
            int jb0 = kst * 32 + kq * 8;
            #pragma unroll
            for (int b = 0; b < 8; ++b) {
                int jb = jb0 + b;
                float sv;
                if (jb < 48) {
                    int jm = (jb < 24) ? jb : jb - 24;
                    float cadd = (jb < 24) ? 0.0f : 0.25f;   // cos = sin(x + 1/4 rev)
                    float rev = __builtin_amdgcn_fractf(fmaf(v, Bs_ls[jm], cadd));
                    sv = __builtin_amdgcn_sinf(rev);
                } else {
                    sv = 0.0f;                               // K-pad 48..63
                }
                split_bf(sv, hu.u[b], lu.u[b]);
            }
            ah[kst] = hu.f; al[kst] = lu.f;
        }

        int e4[4];
        #pragma unroll
        for (int r = 0; r < 4; ++r) {
            int sl = list[cb + kq * 4 + r];
            e4[r] = (sl == 0xFFFF) ? -1 : ((sl >> 6) & 15);
        }

        #pragma unroll 4
        for (int nt = 0; nt < 16; ++nt) {
            int o0 = ((k * 2 + 0) * 16 + nt) * 512 + ln * 8;
            int o1 = ((k * 2 + 1) * 16 + nt) * 512 + ln * 8;
            frag bh0 = *(const frag*)(w1f_hi + o0);
            frag bl0 = *(const frag*)(w1f_lo + o0);
            frag bh1 = *(const frag*)(w1f_hi + o1);
            frag bl1 = *(const frag*)(w1f_lo + o1);
            f32x4 acc = (f32x4)0.0f;
            acc = __builtin_amdgcn_mfma_f32_16x16x32_bf16(ah[0], bh0, acc, 0, 0, 0);
            acc = __builtin_amdgcn_mfma_f32_16x16x32_bf16(al[0], bh0, acc, 0, 0, 0);
            acc = __builtin_amdgcn_mfma_f32_16x16x32_bf16(ah[0], bl0, acc, 0, 0, 0);
            acc = __builtin_amdgcn_mfma_f32_16x16x32_bf16(ah[1], bh1, acc, 0, 0, 0);
            acc = __builtin_amdgcn_mfma_f32_16x16x32_bf16(al[1], bh1, acc, 0, 0, 0);
            acc = __builtin_amdgcn_mfma_f32_16x16x32_bf16(ah[1], bl1, acc, 0, 0, 0);
            float b1v = b1_ls[k * 256 + nt * 16 + lr16];
            #pragma unroll
            for (int r = 0; r < 4; ++r) {
                if (e4[r] >= 0) {
                    float g = gelu_fast(acc[r] + b1v);
                    atomicAdd(&pool_ls[(k * 16 + e4[r]) * PSTR + nt * 16 + lr16], g);
                }
            }
        }
    }
    __syncthreads();

    // ---- fuse phase A: acc = sum_k pool[k] @ w2[k]  (A-frags from fp32 pool) ----
    f32x4 acc[2];
    acc[0] = (f32x4)0.0f; acc[1] = (f32x4)0.0f;

    for (int k = 0; k < 8; ++k) {
        #pragma unroll 2
        for (int kst = 0; kst < 8; ++kst) {
            const float* pp = &pool_ls[(k * 16 + lr16) * PSTR + kst * 32 + kq * 8];
            f32x4 u0 = *(const f32x4*)pp;
            f32x4 u1 = *(const f32x4*)(pp + 4);
            union { unsigned short u[8]; frag f; } hu, lu;
            #pragma unroll
            for (int b = 0; b < 4; ++b) {
                split_bf(u0[b], hu.u[b], lu.u[b]);
                split_bf(u1[b], hu.u[b + 4], lu.u[b + 4]);
            }
            frag ah = hu.f, al = lu.f;
            #pragma unroll
            for (int n = 0; n < 2; ++n) {
                int bo = ((k * 8 + kst) * 16 + (wv * 2 + n)) * 512 + ln * 8;
                frag bh = *(const frag*)(w2f_hi + bo);
                frag bl = *(const frag*)(w2f_lo + bo);
                acc[n] = __builtin_amdgcn_mfma_f32_16x16x32_bf16(ah, bh, acc[n], 0, 0, 0);
                acc[n] = __builtin_amdgcn_mfma_f32_16x16x32_bf16(al, bh, acc[n], 0, 0, 0);
                acc[n] = __builtin_amdgcn_mfma_f32_16x16x32_bf16(ah, bl, acc[n], 0, 0, 0);
            }
        }
    }
    __syncthreads();     // all pool reads done; hz may alias pool head

    float* hz = pool_ls; // [16][256] granule-XOR swizzled

    // ---- epilogue A: + cnt*(b2+kind_emb), * den -> hz ----
    #pragma unroll
    for (int n = 0; n < 2; ++n) {
        int col = (wv * 2 + n) * 16 + lr16;
        float bks[8];
        #pragma unroll
        for (int k = 0; k < 8; ++k) bks[k] = b2[k * 256 + col] + kind_emb[k * 256 + col];
        #pragma unroll
        for (int r = 0; r < 4; ++r) {
            int row = kq * 4 + r;
            float hv = acc[n][r];
            #pragma unroll
            for (int k = 0; k < 8; ++k) hv = fmaf(cnt_ls[row * 8 + k], bks[k], hv);
            hv *= den_ls[row];
            hz[row * 256 + ((((col >> 2) ^ (row & 7)) << 2) | (col & 3))] = hv;
        }
    }
    __syncthreads();

    // ---- phase B: z_pre = [h | type_emb | layer_emb] @ fw1 (K=768) ----
    f32x4 az[2];
    az[0] = (f32x4)0.0f; az[1] = (f32x4)0.0f;

    for (int kst = 0; kst < 24; ++kst) {
        const int row = lr16;
        union { unsigned short u[8]; frag f; } hu, lu;
        if (kst < 8) {
            int c0 = kst * 8 + kq * 2;
            f32x4 u0 = *(const f32x4*)&hz[row * 256 + ((c0 ^ (row & 7)) << 2)];
            f32x4 u1 = *(const f32x4*)&hz[row * 256 + (((c0 + 1) ^ (row & 7)) << 2)];
            #pragma unroll
            for (int b = 0; b < 4; ++b) {
                split_bf(u0[b], hu.u[b], lu.u[b]);
                split_bf(u1[b], hu.u[b + 4], lu.u[b + 4]);
            }
        } else {
            const float* eb = (kst < 16) ? type_emb : layer_emb;
            const int* ids = (kst < 16) ? pt_ls : lid_ls;
            int ko = (kst & 7) * 32 + kq * 8;
            const float* sp = eb + (size_t)ids[row] * 256 + ko;
            f32x4 u0 = *(const f32x4*)sp;
            f32x4 u1 = *(const f32x4*)(sp + 4);
            #pragma unroll
            for (int b = 0; b < 4; ++b) {
                split_bf(u0[b], hu.u[b], lu.u[b]);
                split_bf(u1[b], hu.u[b + 4], lu.u[b + 4]);
            }
        }
        frag ah = hu.f, al = lu.f;
        #pragma unroll
        for (int n = 0; n < 2; ++n) {
            int bo = (kst * 16 + (wv * 2 + n)) * 512 + ln * 8;
            frag bh = *(const frag*)(fw1f_hi + bo);
            frag bl = *(const frag*)(fw1f_lo + bo);
            az[n] = __builtin_amdgcn_mfma_f32_16x16x32_bf16(ah, bh, az[n], 0, 0, 0);
            az[n] = __builtin_amdgcn_mfma_f32_16x16x32_bf16(al, bh, az[n], 0, 0, 0);
            az[n] = __builtin_amdgcn_mfma_f32_16x16x32_bf16(ah, bl, az[n], 0, 0, 0);
        }
    }
    __syncthreads();     // all hz reads done

    #pragma unroll
    for (int n = 0; n < 2; ++n) {
        int col = (wv * 2 + n) * 16 + lr16;
        float fb1v = fb1[col];
        #pragma unroll
        for (int r = 0; r < 4; ++r) {
            int row = kq * 4 + r;
            float z = gelu_fast(az[n][r] + fb1v);
            hz[row * 256 + ((((col >> 2) ^ (row & 7)) << 2) | (col & 3))] = z;
        }
    }
    __syncthreads();

    // ---- phase C: out = z @ fw2 + fb2 + meta @ meta_w + meta_b ----
    f32x4 ao2[2];
    ao2[0] = (f32x4)0.0f; ao2[1] = (f32x4)0.0f;

    for (int kst = 0; kst < 8; ++kst) {
        const int row = lr16;
        int c0 = kst * 8 + kq * 2;
        f32x4 u0 = *(const f32x4*)&hz[row * 256 + ((c0 ^ (row & 7)) << 2)];
        f32x4 u1 = *(const f32x4*)&hz[row * 256 + (((c0 + 1) ^ (row & 7)) << 2)];
        union { unsigned short u[8]; frag f; } hu, lu;
        #pragma unroll
        for (int b = 0; b < 4; ++b) {
            split_bf(u0[b], hu.u[b], lu.u[b]);
            split_bf(u1[b], hu.u[b + 4], lu.u[b + 4]);
        }
        frag ah = hu.f, al = lu.f;
        #pragma unroll
        for (int n = 0; n < 2; ++n) {
            int bo = (kst * 16 + (wv * 2 + n)) * 512 + ln * 8;
            frag bh = *(const frag*)(fw2f_hi + bo);
            frag bl = *(const frag*)(fw2f_lo + bo);
            ao2[n] = __builtin_amdgcn_mfma_f32_16x16x32_bf16(ah, bh, ao2[n], 0, 0, 0);
            ao2[n] = __builtin_amdgcn_mfma_f32_16x16x32_bf16(al, bh, ao2[n], 0, 0, 0);
            ao2[n] = __builtin_amdgcn_mfma_f32_16x16x32_bf16(ah, bl, ao2[n], 0, 0, 0);
        }
    }

    #pragma unroll
    for (int n = 0; n < 2; ++n) {
        int col = (wv * 2 + n) * 16 + lr16;
        float ob = fb2[col] + meta_b[col];
        float mw0 = meta_w[col], mw1 = meta_w[256 + col];
        float mw2 = meta_w[512 + col], mw3 = meta_w[768 + col];
        #pragma unroll
        for (int r = 0; r < 4; ++r) {
            int row = kq * 4 + r;
            float o = ao2[n][r] + ob;
            o = fmaf(meta_ls[row * 4 + 0], mw0, o);
            o = fmaf(meta_ls[row * 4 + 1], mw1, o);
            o = fmaf(meta_ls[row * 4 + 2], mw2, o);
            o = fmaf(meta_ls[row * 4 + 3], mw3, o);
            out[(size_t)(rb + row) * 256 + col] = o;
        }
    }
}

extern "C" void kernel_launch(void* const* d_in, const int* in_sizes, int n_in,
                              void* d_out, int out_size, void* d_ws, size_t ws_size,
                              hipStream_t stream) {
    const float* values    = (const float*)d_in[0];
    const int*   kinds     = (const int*)d_in[1];
    const int*   mask      = (const int*)d_in[2];
    const int*   prim_type = (const int*)d_in[3];
    const int*   layer_id  = (const int*)d_in[4];
    const float* meta      = (const float*)d_in[5];
    const float* B_ff      = (const float*)d_in[6];
    const float* kind_emb  = (const float*)d_in[7];
    const float* type_emb  = (const float*)d_in[8];
    const float* layer_emb = (const float*)d_in[9];
    const float* mlp_w1    = (const float*)d_in[10];
    const float* mlp_b1    = (const float*)d_in[11];
    const float* mlp_w2    = (const float*)d_in[12];
    const float* mlp_b2    = (const float*)d_in[13];
    const float* fuse_w1   = (const float*)d_in[14];
    const float* fuse_b1   = (const float*)d_in[15];
    const float* fuse_w2   = (const float*)d_in[16];
    const float* fuse_b2   = (const float*)d_in[17];
    const float* meta_w    = (const float*)d_in[18];
    const float* meta_b    = (const float*)d_in[19];

    short* ws  = (short*)d_ws;
    float* out = (float*)d_out;

    prep_kernel<<<224, 512, 0, stream>>>(mlp_w1, mlp_w2, fuse_w1, fuse_w2, ws);
    mono_kernel<<<256, 512, 0, stream>>>(values, kinds, mask, B_ff, mlp_b1, ws,
                                         prim_type, layer_id, meta, type_emb,
                                         layer_emb, mlp_b2, kind_emb, fuse_b1,
                                         fuse_b2, meta_w, meta_b, out);
}